// Round 10
// baseline (553.849 us; speedup 1.0000x reference)
//
#include <hip/hip_runtime.h>
#include <math.h>

// Problem constants
#define BSZ 8
#define TT 64
#define NN 64
#define FF 256
#define TWW 8
#define NWW 29
#define LL 512
#define NB (BSZ*NWW)      // 232 window-batches
#define OUTC 128
#define CNTF 118784.0f    // NB*LL

typedef unsigned short u16;
typedef float f32x4 __attribute__((ext_vector_type(4)));
typedef __bf16 bf16x8 __attribute__((ext_vector_type(8)));
#define MFMA16(a,b,c) __builtin_amdgcn_mfma_f32_16x16x32_bf16(a,b,c,0,0,0)

// Tiled layout strides (u16 elements)
#define HT_FT 1048576ull      // Ht[ft][m][fi]: ft stride = 32768*32
#define XT_MT 8192ull         // XTt[mt][f][mi]: mt stride = 256*32
#define TH_FT 4096ull         // THt[ft][o][fi]: ft stride = 128*32

// ws layout (BYTE offsets). PART0/PART1 share region 0 (disjoint lifetimes).
#define B_PART  0              // 1 MB
#define B_SC0   1048576
#define B_SH0   1049600
#define B_SC1   1050624
#define B_SH1   1051136
#define B_HH    1114112        // u16 Ht_hi [8][32768][32] = 16 MB
#define B_HL    17891328
#define B_XTH   34668544       // u16 XTt_hi [1024][256][32] = 16 MB
#define B_XTL   51445760
#define B_THH   68222976       // u16 THt_hi [8][128][32] = 64 KB
#define B_THL   68288512
#define B_OUTP  68354048       // f32[232*512][128] = 60.8 MB

static __device__ __forceinline__ u16 f2bf(float v){
    unsigned int u = __float_as_uint(v);
    return (u16)((u + 0x7FFFu + ((u >> 16) & 1u)) >> 16);   // RNE
}
static __device__ __forceinline__ float bf2f(u16 h){
    return __uint_as_float(((unsigned int)h) << 16);
}

// ---------------- BN0 stats over xc, from x with window multiplicity c(t)
__global__ __launch_bounds__(256) void k_stats0(const float* __restrict__ x, float* __restrict__ part0){
    int bt = blockIdx.x;           // bs*64 + t
    int t  = bt & 63;
    int f  = threadIdx.x;
    const float* xp = x + (size_t)bt * NN * FF + f;
    float s = 0.f, s2 = 0.f;
    #pragma unroll 8
    for (int n = 0; n < NN; ++n){ float v = xp[n*FF]; s += v; s2 += v*v; }
    int wmin = (t >= 7) ? ((t - 6) >> 1) : 0;
    int wmax = t >> 1; if (wmax > 28) wmax = 28;
    float c = (float)(wmax - wmin + 1);
    part0[bt*512 + f]       = c * s;
    part0[bt*512 + 256 + f] = c * s2;
}

__global__ __launch_bounds__(256) void k_fin0(const float* __restrict__ part0,
                                              const float* __restrict__ gamma, const float* __restrict__ beta,
                                              float* __restrict__ sc0, float* __restrict__ sh0){
    int f = threadIdx.x;
    float S = 0.f, S2 = 0.f;
    for (int b = 0; b < 512; ++b){ S += part0[b*512 + f]; S2 += part0[b*512 + 256 + f]; }
    float mean = S / CNTF;
    float var  = S2 / CNTF - mean*mean;
    float sc   = gamma[f] * rsqrtf(var + 1e-5f);
    sc0[f] = sc;
    sh0[f] = beta[f] - mean*sc;
}

// ---------------- theta split + transpose + f-tile: THt[f>>5][o][f&31]
__global__ __launch_bounds__(256) void k_prep(const float* __restrict__ th,
                                              u16* __restrict__ Th, u16* __restrict__ Tl){
    int idx = blockIdx.x*256 + threadIdx.x;   // 128 blocks -> 32768
    int o = idx >> 8;        // 0..127
    int f = idx & 255;
    float v = th[f*128 + o];
    u16 h = f2bf(v);
    size_t a = (size_t)(f>>5)*TH_FT + o*32 + (f&31);
    Th[a] = h;
    Tl[a] = f2bf(v - bf2f(h));
}

// ---------------- H = x@W_map + b_map -> Ht (f-tiled, split bf16);
//                  XNT = (x*sc0+sh0) -> XTt (m-tiled transposed, split bf16)
__global__ __launch_bounds__(256,2) void k_map(const float* __restrict__ x, const float* __restrict__ Wm,
                                               const float* __restrict__ bm,
                                               const float* __restrict__ sc0, const float* __restrict__ sh0,
                                               u16* __restrict__ Hh, u16* __restrict__ Hl,
                                               u16* __restrict__ XTh, u16* __restrict__ XTl){
    __shared__ float xs[64*260];
    int bt  = blockIdx.x;
    int tid = threadIdx.x;
    size_t base = (size_t)bt * NN * FF;
    {   // stage x tile
        int r  = tid >> 2;
        int f0 = (tid & 3) << 6;
        const float* src = x + base + r*FF + f0;
        #pragma unroll
        for (int it = 0; it < 16; ++it){
            int f = f0 + it*4;
            float4 v = *(const float4*)(src + it*4);
            xs[r*260 + f]   = v.x; xs[r*260 + f+1] = v.y;
            xs[r*260 + f+2] = v.z; xs[r*260 + f+3] = v.w;
        }
    }
    __syncthreads();
    // H GEMM (fp32 in regs), split-store bf16 hi/lo to tiled layout
    int r0 = (tid >> 6) << 4;
    int c0 = (tid & 63) << 2;
    float4 bm4 = *(const float4*)(bm + c0);
    float acc[16][4];
    #pragma unroll
    for (int u = 0; u < 16; ++u){ acc[u][0]=bm4.x; acc[u][1]=bm4.y; acc[u][2]=bm4.z; acc[u][3]=bm4.w; }
    #pragma unroll 2
    for (int k = 0; k < 256; ++k){
        float4 wv = *(const float4*)(Wm + k*FF + c0);
        #pragma unroll
        for (int u = 0; u < 16; ++u){
            float xv = xs[(r0+u)*260 + k];
            acc[u][0] += xv*wv.x; acc[u][1] += xv*wv.y;
            acc[u][2] += xv*wv.z; acc[u][3] += xv*wv.w;
        }
    }
    size_t hbase = (size_t)(c0>>5)*HT_FT + (c0&31);
    #pragma unroll
    for (int u = 0; u < 16; ++u){
        size_t idx = hbase + (size_t)(bt*64 + r0 + u)*32;
        u16 h0=f2bf(acc[u][0]), h1=f2bf(acc[u][1]), h2=f2bf(acc[u][2]), h3=f2bf(acc[u][3]);
        u16 l0=f2bf(acc[u][0]-bf2f(h0)), l1=f2bf(acc[u][1]-bf2f(h1));
        u16 l2=f2bf(acc[u][2]-bf2f(h2)), l3=f2bf(acc[u][3]-bf2f(h3));
        uint2 vh; vh.x = (unsigned)h0 | ((unsigned)h1<<16); vh.y = (unsigned)h2 | ((unsigned)h3<<16);
        uint2 vl; vl.x = (unsigned)l0 | ((unsigned)l1<<16); vl.y = (unsigned)l2 | ((unsigned)l3<<16);
        *(uint2*)(Hh + idx) = vh;
        *(uint2*)(Hl + idx) = vl;
    }
    // XNT: thread owns feature f = tid; write bf16 hi/lo into m-tiled transpose
    {
        int f = tid;
        float sc = sc0[f], sh = sh0[f];
        #pragma unroll
        for (int rr = 0; rr < 16; ++rr){
            int n = rr*4;
            float v0 = xs[(n  )*260 + f]*sc + sh;
            float v1 = xs[(n+1)*260 + f]*sc + sh;
            float v2 = xs[(n+2)*260 + f]*sc + sh;
            float v3 = xs[(n+3)*260 + f]*sc + sh;
            u16 h0=f2bf(v0), h1=f2bf(v1), h2=f2bf(v2), h3=f2bf(v3);
            u16 l0=f2bf(v0-bf2f(h0)), l1=f2bf(v1-bf2f(h1)), l2=f2bf(v2-bf2f(h2)), l3=f2bf(v3-bf2f(h3));
            uint2 vh; vh.x = (unsigned)h0 | ((unsigned)h1<<16); vh.y = (unsigned)h2 | ((unsigned)h3<<16);
            uint2 vl; vl.x = (unsigned)l0 | ((unsigned)l1<<16); vl.y = (unsigned)l2 | ((unsigned)l3<<16);
            size_t o = (size_t)(bt*2 + (n>>5))*XT_MT + f*32 + (n&31);
            *(uint2*)(XTh + o) = vh;
            *(uint2*)(XTl + o) = vl;
        }
    }
}

// ---------------- fused MFMA attention with ping-pong fragment prefetch.
// Phase 1/3/4 loads for iteration k+1 are issued BEFORE the MFMAs of k,
// so L2 latency hides under the matrix pipe. Addresses identical to R9.
__global__ __launch_bounds__(512,4) void k_attn(const u16* __restrict__ Hh, const u16* __restrict__ Hl,
                                                const u16* __restrict__ XTh, const u16* __restrict__ XTl,
                                                const u16* __restrict__ THh, const u16* __restrict__ THl,
                                                const float* __restrict__ thb,
                                                float* __restrict__ outp){
    __shared__ float smem[16384];   // 64KB: S[32][512]f32 -> P_hi/P_lo bf16 -> ax_hi/lo bf16
    char* sb = (char*)smem;
    // XCD-aware remap (bijective: 3712 = 8 XCDs * 464)
    int i    = blockIdx.x;
    int k_   = i >> 3;
    int bw   = (i & 7) * 29 + (k_ >> 4);
    int tile = k_ & 15;
    int bs   = bw / NWW;
    int w    = bw - bs*NWW;
    int g0   = bs*4096 + w*128;     // window slab base row
    int g032 = bs*128 + w*4;        // g0/32 (m-tile base)
    int tid = threadIdx.x, lane = tid & 63, wid = tid >> 6;
    int lr = lane & 15, g = lane >> 4;

    // ---- Phase 1: S = Q K^T via MFMA; B double-buffered, A single (L1-shared by 8 waves)
    f32x4 acc[2][4];
    #pragma unroll
    for (int qt = 0; qt < 2; ++qt)
        #pragma unroll
        for (int j = 0; j < 4; ++j) acc[qt][j] = (f32x4){0.f,0.f,0.f,0.f};

    int qrow = g0 + tile*32 + lr;
    int brow = g0 + wid*64 + lr;
    {
        bf16x8 A0h, A0l, A1h, A1l;
        bf16x8 cB0h,cB0l,cB1h,cB1l,cB2h,cB2l,cB3h,cB3l;
        bf16x8 nB0h,nB0l,nB1h,nB1l,nB2h,nB2l,nB3h,nB3l;

#define LDA1(KS) { size_t ta=(size_t)(KS)*HT_FT + g*8 + (size_t)qrow*32; \
        A0h=*(const bf16x8*)(Hh+ta);        A0l=*(const bf16x8*)(Hl+ta); \
        A1h=*(const bf16x8*)(Hh+ta+512);    A1l=*(const bf16x8*)(Hl+ta+512); }
#define LDB1(P, KS) { size_t tb=(size_t)(KS)*HT_FT + g*8 + (size_t)brow*32; \
        P##B0h=*(const bf16x8*)(Hh+tb);       P##B0l=*(const bf16x8*)(Hl+tb); \
        P##B1h=*(const bf16x8*)(Hh+tb+512);   P##B1l=*(const bf16x8*)(Hl+tb+512); \
        P##B2h=*(const bf16x8*)(Hh+tb+1024);  P##B2l=*(const bf16x8*)(Hl+tb+1024); \
        P##B3h=*(const bf16x8*)(Hh+tb+1536);  P##B3l=*(const bf16x8*)(Hl+tb+1536); }
#define MM1(P) { \
        acc[0][0]=MFMA16(A0h,P##B0h,acc[0][0]); acc[0][0]=MFMA16(A0h,P##B0l,acc[0][0]); acc[0][0]=MFMA16(A0l,P##B0h,acc[0][0]); \
        acc[1][0]=MFMA16(A1h,P##B0h,acc[1][0]); acc[1][0]=MFMA16(A1h,P##B0l,acc[1][0]); acc[1][0]=MFMA16(A1l,P##B0h,acc[1][0]); \
        acc[0][1]=MFMA16(A0h,P##B1h,acc[0][1]); acc[0][1]=MFMA16(A0h,P##B1l,acc[0][1]); acc[0][1]=MFMA16(A0l,P##B1h,acc[0][1]); \
        acc[1][1]=MFMA16(A1h,P##B1h,acc[1][1]); acc[1][1]=MFMA16(A1h,P##B1l,acc[1][1]); acc[1][1]=MFMA16(A1l,P##B1h,acc[1][1]); \
        acc[0][2]=MFMA16(A0h,P##B2h,acc[0][2]); acc[0][2]=MFMA16(A0h,P##B2l,acc[0][2]); acc[0][2]=MFMA16(A0l,P##B2h,acc[0][2]); \
        acc[1][2]=MFMA16(A1h,P##B2h,acc[1][2]); acc[1][2]=MFMA16(A1h,P##B2l,acc[1][2]); acc[1][2]=MFMA16(A1l,P##B2h,acc[1][2]); \
        acc[0][3]=MFMA16(A0h,P##B3h,acc[0][3]); acc[0][3]=MFMA16(A0h,P##B3l,acc[0][3]); acc[0][3]=MFMA16(A0l,P##B3h,acc[0][3]); \
        acc[1][3]=MFMA16(A1h,P##B3h,acc[1][3]); acc[1][3]=MFMA16(A1h,P##B3l,acc[1][3]); acc[1][3]=MFMA16(A1l,P##B3h,acc[1][3]); }

        LDA1(0); LDB1(c,0);
        #pragma unroll
        for (int ks = 0; ks < 8; ks += 2){
            LDB1(n, ks+1);                 // prefetch next-ks B under current MFMAs
            MM1(c);
            LDA1(ks+1);
            if (ks < 6) LDB1(c, ks+2);     // prefetch ks+2 under ks+1 MFMAs
            MM1(n);
            if (ks < 6) LDA1(ks+2);
        }
#undef LDA1
#undef LDB1
#undef MM1
    }
    // store S[32][512] f32, byte = (q*2048 + m*4) ^ ((q&7)<<4)
    #pragma unroll
    for (int qt = 0; qt < 2; ++qt)
        #pragma unroll
        for (int j = 0; j < 4; ++j){
            int m = (wid*4 + j)*16 + lr;
            #pragma unroll
            for (int r = 0; r < 4; ++r){
                int q = qt*16 + g*4 + r;
                *(float*)(sb + (((q<<11) + (m<<2)) ^ ((q&7)<<4))) = acc[qt][j][r];
            }
        }
    __syncthreads();

    // ---- Phase 2: softmax * decay (+eye), rows wid*4..+3, lane holds m = 4*lane+jj, 256+4*lane+jj
    float sacc[4][8];
    int mlo = lane << 2;
    int lbase = tile*32 + wid*4;
    int twl   = lbase >> 6;
    const float LOG2D = -0.5145731728297583f;    // log2(0.7)
    float dm0 = exp2f(LOG2D * fabsf((float)(twl - (lane >> 4))));
    float dm1 = exp2f(LOG2D * fabsf((float)(twl - 4 - (lane >> 4))));
    #pragma unroll
    for (int li = 0; li < 4; ++li){
        int q  = wid*4 + li;
        int lg = tile*32 + q;
        int b0 = ((q<<11) + (mlo<<2)) ^ ((q&7)<<4);
        int b1 = ((q<<11) + 1024 + (mlo<<2)) ^ ((q&7)<<4);
        f32x4 s0 = *(const f32x4*)(sb + b0);
        f32x4 s1 = *(const f32x4*)(sb + b1);
        sacc[li][0]=s0[0]; sacc[li][1]=s0[1]; sacc[li][2]=s0[2]; sacc[li][3]=s0[3];
        sacc[li][4]=s1[0]; sacc[li][5]=s1[1]; sacc[li][6]=s1[2]; sacc[li][7]=s1[3];
        #pragma unroll
        for (int jj = 0; jj < 8; ++jj){
            float v = sacc[li][jj];
            int m = ((jj >> 2) << 8) + mlo + (jj & 3);
            if (m == lg) v -= 1e8f;
            v = (v > 0.f) ? v : 0.01f*v;
            sacc[li][jj] = v;
        }
        float mx = sacc[li][0];
        #pragma unroll
        for (int jj = 1; jj < 8; ++jj) mx = fmaxf(mx, sacc[li][jj]);
        #pragma unroll
        for (int off = 32; off >= 1; off >>= 1) mx = fmaxf(mx, __shfl_xor(mx, off, 64));
        float sum = 0.f;
        #pragma unroll
        for (int jj = 0; jj < 8; ++jj){ float e = __expf(sacc[li][jj] - mx); sacc[li][jj] = e; sum += e; }
        #pragma unroll
        for (int off = 32; off >= 1; off >>= 1) sum += __shfl_xor(sum, off, 64);
        float inv = 1.f / sum;
        float f0m = inv * dm0, f1m = inv * dm1;
        sacc[li][0]*=f0m; sacc[li][1]*=f0m; sacc[li][2]*=f0m; sacc[li][3]*=f0m;
        sacc[li][4]*=f1m; sacc[li][5]*=f1m; sacc[li][6]*=f1m; sacc[li][7]*=f1m;
        #pragma unroll
        for (int jj = 0; jj < 8; ++jj){   // + eye (mask diag == 1); softmax diag is exactly 0
            int m = ((jj >> 2) << 8) + mlo + (jj & 3);
            if (m == lg) sacc[li][jj] += 1.0f;
        }
    }
    __syncthreads();   // all waves done reading S

    // write P_hi[32][512]bf16 @0, P_lo @+32KB; byte = (q*1024 + m*2) ^ ((q&7)<<4)
    #pragma unroll
    for (int li = 0; li < 4; ++li){
        int q = wid*4 + li;
        int swz = (q&7) << 4;
        int bA = ((q<<10) + (lane<<3)) ^ swz;
        int bB = ((q<<10) + 512 + (lane<<3)) ^ swz;
        u16 h[8], l[8];
        #pragma unroll
        for (int jj = 0; jj < 8; ++jj){
            float v = sacc[li][jj];
            h[jj] = f2bf(v);
            l[jj] = f2bf(v - bf2f(h[jj]));
        }
        uint2 vh0; vh0.x=(unsigned)h[0]|((unsigned)h[1]<<16); vh0.y=(unsigned)h[2]|((unsigned)h[3]<<16);
        uint2 vh1; vh1.x=(unsigned)h[4]|((unsigned)h[5]<<16); vh1.y=(unsigned)h[6]|((unsigned)h[7]<<16);
        uint2 vl0; vl0.x=(unsigned)l[0]|((unsigned)l[1]<<16); vl0.y=(unsigned)l[2]|((unsigned)l[3]<<16);
        uint2 vl1; vl1.x=(unsigned)l[4]|((unsigned)l[5]<<16); vl1.y=(unsigned)l[6]|((unsigned)l[7]<<16);
        *(uint2*)(sb + bA)         = vh0;
        *(uint2*)(sb + bB)         = vh1;
        *(uint2*)(sb + 32768 + bA) = vl0;
        *(uint2*)(sb + 32768 + bB) = vl1;
    }
    __syncthreads();   // P ready

    // ---- Phase 3: ax = P @ XN via MFMA; P(LDS) and V(XTt) both double-buffered
    f32x4 acc2[2][2];
    #pragma unroll
    for (int qt = 0; qt < 2; ++qt){ acc2[qt][0]=(f32x4){0.f,0.f,0.f,0.f}; acc2[qt][1]=(f32x4){0.f,0.f,0.f,0.f}; }
    int frow = wid*32 + lr;
    {
        bf16x8 cp0h,cp0l,cp1h,cp1l, cv0h,cv0l,cv1h,cv1l;
        bf16x8 np0h,np0l,np1h,np1l, nv0h,nv0l,nv1h,nv1l;

#define LDP3(P, KS) { \
        int pb = (((lr<<10) + (KS)*64 + (g<<4))) ^ ((lr&7)<<4); \
        P##p0h=*(const bf16x8*)(sb + pb);          P##p0l=*(const bf16x8*)(sb + 32768 + pb); \
        P##p1h=*(const bf16x8*)(sb + 16384 + pb);  P##p1l=*(const bf16x8*)(sb + 49152 + pb); \
        size_t vb = (size_t)(g032 + (KS))*XT_MT + g*8 + (size_t)frow*32; \
        P##v0h=*(const bf16x8*)(XTh + vb);         P##v0l=*(const bf16x8*)(XTl + vb); \
        P##v1h=*(const bf16x8*)(XTh + vb + 512);   P##v1l=*(const bf16x8*)(XTl + vb + 512); }
#define MM3(P) { \
        acc2[0][0]=MFMA16(P##p0h,P##v0h,acc2[0][0]); acc2[0][0]=MFMA16(P##p0h,P##v0l,acc2[0][0]); acc2[0][0]=MFMA16(P##p0l,P##v0h,acc2[0][0]); \
        acc2[1][0]=MFMA16(P##p1h,P##v0h,acc2[1][0]); acc2[1][0]=MFMA16(P##p1h,P##v0l,acc2[1][0]); acc2[1][0]=MFMA16(P##p1l,P##v0h,acc2[1][0]); \
        acc2[0][1]=MFMA16(P##p0h,P##v1h,acc2[0][1]); acc2[0][1]=MFMA16(P##p0h,P##v1l,acc2[0][1]); acc2[0][1]=MFMA16(P##p0l,P##v1h,acc2[0][1]); \
        acc2[1][1]=MFMA16(P##p1h,P##v1h,acc2[1][1]); acc2[1][1]=MFMA16(P##p1h,P##v1l,acc2[1][1]); acc2[1][1]=MFMA16(P##p1l,P##v1h,acc2[1][1]); }

        LDP3(c,0);
        #pragma unroll
        for (int ks = 0; ks < 16; ks += 2){
            LDP3(n, ks+1);
            MM3(c);
            if (ks < 14) LDP3(c, ks+2);
            MM3(n);
        }
#undef LDP3
#undef MM3
    }
    __syncthreads();   // done reading P

    // write ax_hi[32][256]bf16 @0, ax_lo @+16KB; byte = (q*512 + f*2) ^ ((q&7)<<4)
    #pragma unroll
    for (int qt = 0; qt < 2; ++qt)
        #pragma unroll
        for (int jn = 0; jn < 2; ++jn){
            int f = (wid*2 + jn)*16 + lr;
            #pragma unroll
            for (int r = 0; r < 4; ++r){
                int q = qt*16 + g*4 + r;
                float v = acc2[qt][jn][r];
                u16 h = f2bf(v);
                int byte = ((q<<9) + (f<<1)) ^ ((q&7)<<4);
                *(u16*)(sb + byte)         = h;
                *(u16*)(sb + 16384 + byte) = f2bf(v - bf2f(h));
            }
        }
    __syncthreads();   // ax ready

    // ---- Phase 4: out_pre = ax @ theta + thb via MFMA; double-buffered
    f32x4 acc3[2];
    acc3[0] = (f32x4){0.f,0.f,0.f,0.f};
    acc3[1] = (f32x4){0.f,0.f,0.f,0.f};
    int orow = wid*16 + lr;
    {
        bf16x8 ca0h,ca0l,ca1h,ca1l, cbh,cbl;
        bf16x8 na0h,na0l,na1h,na1l, nbh,nbl;

#define LDP4(P, KS) { \
        int ab = (((lr<<9) + (KS)*64 + (g<<4))) ^ ((lr&7)<<4); \
        P##a0h=*(const bf16x8*)(sb + ab);         P##a0l=*(const bf16x8*)(sb + 16384 + ab); \
        P##a1h=*(const bf16x8*)(sb + 8192 + ab);  P##a1l=*(const bf16x8*)(sb + 24576 + ab); \
        size_t tb = (size_t)(KS)*TH_FT + (size_t)orow*32 + g*8; \
        P##bh=*(const bf16x8*)(THh + tb);         P##bl=*(const bf16x8*)(THl + tb); }
#define MM4(P) { \
        acc3[0]=MFMA16(P##a0h,P##bh,acc3[0]); acc3[0]=MFMA16(P##a0h,P##bl,acc3[0]); acc3[0]=MFMA16(P##a0l,P##bh,acc3[0]); \
        acc3[1]=MFMA16(P##a1h,P##bh,acc3[1]); acc3[1]=MFMA16(P##a1h,P##bl,acc3[1]); acc3[1]=MFMA16(P##a1l,P##bh,acc3[1]); }

        LDP4(c,0);
        #pragma unroll
        for (int ks = 0; ks < 8; ks += 2){
            LDP4(n, ks+1);
            MM4(c);
            if (ks < 6) LDP4(c, ks+2);
            MM4(n);
        }
#undef LDP4
#undef MM4
    }
    float tb2 = thb[orow];
    #pragma unroll
    for (int qt = 0; qt < 2; ++qt)
        #pragma unroll
        for (int r = 0; r < 4; ++r){
            int q = qt*16 + g*4 + r;
            size_t R = (size_t)bw*512 + tile*32 + q;
            outp[R*128 + orow] = acc3[qt][r] + tb2;
        }
}

// ---------------- BN1 stats over out_pre (deterministic two-stage)
__global__ __launch_bounds__(256) void k_stats1(const float* __restrict__ outp, float* __restrict__ part1){
    __shared__ float rs[256], rs2[256];
    int tid = threadIdx.x;
    int ch = tid & 127, rh = tid >> 7;
    size_t base = (size_t)blockIdx.x * 116;
    float s = 0.f, s2 = 0.f;
    for (int i = 0; i < 58; ++i){
        float v = outp[(base + rh + 2*i)*128 + ch];
        s += v; s2 += v*v;
    }
    rs[tid] = s; rs2[tid] = s2;
    __syncthreads();
    if (tid < 128){
        part1[blockIdx.x*256 + tid]       = rs[tid] + rs[tid+128];
        part1[blockIdx.x*256 + 128 + tid] = rs2[tid] + rs2[tid+128];
    }
}

__global__ __launch_bounds__(128) void k_fin1(const float* __restrict__ part1,
                                              const float* __restrict__ g1, const float* __restrict__ b1,
                                              float* __restrict__ sc1, float* __restrict__ sh1){
    int ch = threadIdx.x;
    float S = 0.f, S2 = 0.f;
    for (int b = 0; b < 1024; ++b){ S += part1[b*256 + ch]; S2 += part1[b*256 + 128 + ch]; }
    float mean = S / CNTF;
    float var  = S2 / CNTF - mean*mean;
    float sc = g1[ch] * rsqrtf(var + 1e-5f);
    sc1[ch] = sc;
    sh1[ch] = b1[ch] - mean*sc;
}

// ---------------- BN1 apply + leaky + mean-pool over tw
__global__ __launch_bounds__(256) void k_epi(const float* __restrict__ outp,
                                             const float* __restrict__ sc1, const float* __restrict__ sh1,
                                             float* __restrict__ out){
    int idx = blockIdx.x*256 + threadIdx.x;   // < 1900544
    int o = idx & 127;
    int rest = idx >> 7;
    int n = rest & 63;
    int bwq = rest >> 6;
    float sc = sc1[o], sh = sh1[o];
    size_t rowb = ((size_t)bwq*512 + n)*128 + o;
    float acc = 0.f;
    #pragma unroll
    for (int tw = 0; tw < 8; ++tw){
        float v = outp[rowb + (size_t)tw*64*128];
        v = v*sc + sh;
        v = (v > 0.f) ? v : 0.01f*v;
        acc += v;
    }
    out[idx] = acc * 0.125f;
}

extern "C" void kernel_launch(void* const* d_in, const int* in_sizes, int n_in,
                              void* d_out, int out_size, void* d_ws, size_t ws_size,
                              hipStream_t stream) {
    const float* x   = (const float*)d_in[0];
    const float* Wm  = (const float*)d_in[1];
    const float* bm  = (const float*)d_in[2];
    const float* g0  = (const float*)d_in[3];
    const float* b0  = (const float*)d_in[4];
    const float* th  = (const float*)d_in[5];
    const float* thb = (const float*)d_in[6];
    const float* g1  = (const float*)d_in[7];
    const float* b1  = (const float*)d_in[8];
    char* wsb  = (char*)d_ws;
    float* out = (float*)d_out;

    float* part = (float*)(wsb + B_PART);
    float* sc0  = (float*)(wsb + B_SC0);
    float* sh0  = (float*)(wsb + B_SH0);
    float* sc1  = (float*)(wsb + B_SC1);
    float* sh1  = (float*)(wsb + B_SH1);
    u16* Hh  = (u16*)(wsb + B_HH);
    u16* Hl  = (u16*)(wsb + B_HL);
    u16* XTh = (u16*)(wsb + B_XTH);
    u16* XTl = (u16*)(wsb + B_XTL);
    u16* THh = (u16*)(wsb + B_THH);
    u16* THl = (u16*)(wsb + B_THL);
    float* outp = (float*)(wsb + B_OUTP);

    hipLaunchKernelGGL(k_stats0, dim3(512),  dim3(256), 0, stream, x, part);
    hipLaunchKernelGGL(k_fin0,   dim3(1),    dim3(256), 0, stream, part, g0, b0, sc0, sh0);
    hipLaunchKernelGGL(k_prep,   dim3(128),  dim3(256), 0, stream, th, THh, THl);
    hipLaunchKernelGGL(k_map,    dim3(512),  dim3(256), 0, stream, x, Wm, bm, sc0, sh0, Hh, Hl, XTh, XTl);
    hipLaunchKernelGGL(k_attn,   dim3(3712), dim3(512), 0, stream, Hh, Hl, XTh, XTl, THh, THl, thb, outp);
    hipLaunchKernelGGL(k_stats1, dim3(1024), dim3(256), 0, stream, outp, part);
    hipLaunchKernelGGL(k_fin1,   dim3(1),    dim3(128), 0, stream, part, g1, b1, sc1, sh1);
    hipLaunchKernelGGL(k_epi,    dim3(7424), dim3(256), 0, stream, outp, sc1, sh1, out);
}

// Round 12
// 547.151 us; speedup vs baseline: 1.0122x; 1.0122x over previous
//
#include <hip/hip_runtime.h>
#include <math.h>

// Problem constants
#define BSZ 8
#define TT 64
#define NN 64
#define FF 256
#define TWW 8
#define NWW 29
#define LL 512
#define NB (BSZ*NWW)      // 232 window-batches
#define OUTC 128
#define CNTF 118784.0f    // NB*LL

typedef unsigned short u16;
typedef float f32x4 __attribute__((ext_vector_type(4)));
typedef __bf16 bf16x8 __attribute__((ext_vector_type(8)));
#define MFMA16(a,b,c) __builtin_amdgcn_mfma_f32_16x16x32_bf16(a,b,c,0,0,0)
#define SBAR() __builtin_amdgcn_sched_barrier(0)

// Tiled layout strides (u16 elements)
#define HT_FT 1048576ull      // Ht[ft][m][fi]: ft stride = 32768*32
#define XT_MT 8192ull         // XTt[mt][f][mi]: mt stride = 256*32
#define TH_FT 4096ull         // THt[ft][o][fi]: ft stride = 128*32

// ws layout (BYTE offsets). PART0/PART1 share region 0 (disjoint lifetimes).
#define B_PART  0              // 1 MB
#define B_SC0   1048576
#define B_SH0   1049600
#define B_SC1   1050624
#define B_SH1   1051136
#define B_HH    1114112        // u16 Ht_hi [8][32768][32] = 16 MB
#define B_HL    17891328
#define B_XTH   34668544       // u16 XTt_hi [1024][256][32] = 16 MB
#define B_XTL   51445760
#define B_THH   68222976       // u16 THt_hi [8][128][32] = 64 KB
#define B_THL   68288512
#define B_OUTP  68354048       // f32[232*512][128] = 60.8 MB

static __device__ __forceinline__ u16 f2bf(float v){
    unsigned int u = __float_as_uint(v);
    return (u16)((u + 0x7FFFu + ((u >> 16) & 1u)) >> 16);   // RNE
}
static __device__ __forceinline__ float bf2f(u16 h){
    return __uint_as_float(((unsigned int)h) << 16);
}

// ---------------- BN0 stats over xc, from x with window multiplicity c(t)
__global__ __launch_bounds__(256) void k_stats0(const float* __restrict__ x, float* __restrict__ part0){
    int bt = blockIdx.x;           // bs*64 + t
    int t  = bt & 63;
    int f  = threadIdx.x;
    const float* xp = x + (size_t)bt * NN * FF + f;
    float s = 0.f, s2 = 0.f;
    #pragma unroll 8
    for (int n = 0; n < NN; ++n){ float v = xp[n*FF]; s += v; s2 += v*v; }
    int wmin = (t >= 7) ? ((t - 6) >> 1) : 0;
    int wmax = t >> 1; if (wmax > 28) wmax = 28;
    float c = (float)(wmax - wmin + 1);
    part0[bt*512 + f]       = c * s;
    part0[bt*512 + 256 + f] = c * s2;
}

__global__ __launch_bounds__(256) void k_fin0(const float* __restrict__ part0,
                                              const float* __restrict__ gamma, const float* __restrict__ beta,
                                              float* __restrict__ sc0, float* __restrict__ sh0){
    int f = threadIdx.x;
    float S = 0.f, S2 = 0.f;
    for (int b = 0; b < 512; ++b){ S += part0[b*512 + f]; S2 += part0[b*512 + 256 + f]; }
    float mean = S / CNTF;
    float var  = S2 / CNTF - mean*mean;
    float sc   = gamma[f] * rsqrtf(var + 1e-5f);
    sc0[f] = sc;
    sh0[f] = beta[f] - mean*sc;
}

// ---------------- theta split + transpose + f-tile: THt[f>>5][o][f&31]
__global__ __launch_bounds__(256) void k_prep(const float* __restrict__ th,
                                              u16* __restrict__ Th, u16* __restrict__ Tl){
    int idx = blockIdx.x*256 + threadIdx.x;   // 128 blocks -> 32768
    int o = idx >> 8;        // 0..127
    int f = idx & 255;
    float v = th[f*128 + o];
    u16 h = f2bf(v);
    size_t a = (size_t)(f>>5)*TH_FT + o*32 + (f&31);
    Th[a] = h;
    Tl[a] = f2bf(v - bf2f(h));
}

// ---------------- H = x@W_map + b_map -> Ht (f-tiled, split bf16);
//                  XNT = (x*sc0+sh0) -> XTt (m-tiled transposed, split bf16)
__global__ __launch_bounds__(256,2) void k_map(const float* __restrict__ x, const float* __restrict__ Wm,
                                               const float* __restrict__ bm,
                                               const float* __restrict__ sc0, const float* __restrict__ sh0,
                                               u16* __restrict__ Hh, u16* __restrict__ Hl,
                                               u16* __restrict__ XTh, u16* __restrict__ XTl){
    __shared__ float xs[64*260];
    int bt  = blockIdx.x;
    int tid = threadIdx.x;
    size_t base = (size_t)bt * NN * FF;
    {   // stage x tile
        int r  = tid >> 2;
        int f0 = (tid & 3) << 6;
        const float* src = x + base + r*FF + f0;
        #pragma unroll
        for (int it = 0; it < 16; ++it){
            int f = f0 + it*4;
            float4 v = *(const float4*)(src + it*4);
            xs[r*260 + f]   = v.x; xs[r*260 + f+1] = v.y;
            xs[r*260 + f+2] = v.z; xs[r*260 + f+3] = v.w;
        }
    }
    __syncthreads();
    // H GEMM (fp32 in regs), split-store bf16 hi/lo to tiled layout
    int r0 = (tid >> 6) << 4;
    int c0 = (tid & 63) << 2;
    float4 bm4 = *(const float4*)(bm + c0);
    float acc[16][4];
    #pragma unroll
    for (int u = 0; u < 16; ++u){ acc[u][0]=bm4.x; acc[u][1]=bm4.y; acc[u][2]=bm4.z; acc[u][3]=bm4.w; }
    #pragma unroll 2
    for (int k = 0; k < 256; ++k){
        float4 wv = *(const float4*)(Wm + k*FF + c0);
        #pragma unroll
        for (int u = 0; u < 16; ++u){
            float xv = xs[(r0+u)*260 + k];
            acc[u][0] += xv*wv.x; acc[u][1] += xv*wv.y;
            acc[u][2] += xv*wv.z; acc[u][3] += xv*wv.w;
        }
    }
    size_t hbase = (size_t)(c0>>5)*HT_FT + (c0&31);
    #pragma unroll
    for (int u = 0; u < 16; ++u){
        size_t idx = hbase + (size_t)(bt*64 + r0 + u)*32;
        u16 h0=f2bf(acc[u][0]), h1=f2bf(acc[u][1]), h2=f2bf(acc[u][2]), h3=f2bf(acc[u][3]);
        u16 l0=f2bf(acc[u][0]-bf2f(h0)), l1=f2bf(acc[u][1]-bf2f(h1));
        u16 l2=f2bf(acc[u][2]-bf2f(h2)), l3=f2bf(acc[u][3]-bf2f(h3));
        uint2 vh; vh.x = (unsigned)h0 | ((unsigned)h1<<16); vh.y = (unsigned)h2 | ((unsigned)h3<<16);
        uint2 vl; vl.x = (unsigned)l0 | ((unsigned)l1<<16); vl.y = (unsigned)l2 | ((unsigned)l3<<16);
        *(uint2*)(Hh + idx) = vh;
        *(uint2*)(Hl + idx) = vl;
    }
    // XNT: thread owns feature f = tid; write bf16 hi/lo into m-tiled transpose
    {
        int f = tid;
        float sc = sc0[f], sh = sh0[f];
        #pragma unroll
        for (int rr = 0; rr < 16; ++rr){
            int n = rr*4;
            float v0 = xs[(n  )*260 + f]*sc + sh;
            float v1 = xs[(n+1)*260 + f]*sc + sh;
            float v2 = xs[(n+2)*260 + f]*sc + sh;
            float v3 = xs[(n+3)*260 + f]*sc + sh;
            u16 h0=f2bf(v0), h1=f2bf(v1), h2=f2bf(v2), h3=f2bf(v3);
            u16 l0=f2bf(v0-bf2f(h0)), l1=f2bf(v1-bf2f(h1)), l2=f2bf(v2-bf2f(h2)), l3=f2bf(v3-bf2f(h3));
            uint2 vh; vh.x = (unsigned)h0 | ((unsigned)h1<<16); vh.y = (unsigned)h2 | ((unsigned)h3<<16);
            uint2 vl; vl.x = (unsigned)l0 | ((unsigned)l1<<16); vl.y = (unsigned)l2 | ((unsigned)l3<<16);
            size_t o = (size_t)(bt*2 + (n>>5))*XT_MT + f*32 + (n&31);
            *(uint2*)(XTh + o) = vh;
            *(uint2*)(XTl + o) = vl;
        }
    }
}

// ---------------- fused MFMA attention; ping-pong prefetch PINNED by sched_barrier(0).
// The fence after each prefetch group prevents the loads from sinking past the
// MFMA block -> double-buffer live ranges are forced -> counted waitcnt, latency
// hidden under MFMA. Addresses identical to R9/R10.
__global__ __launch_bounds__(512,4) void k_attn(const u16* __restrict__ Hh, const u16* __restrict__ Hl,
                                                const u16* __restrict__ XTh, const u16* __restrict__ XTl,
                                                const u16* __restrict__ THh, const u16* __restrict__ THl,
                                                const float* __restrict__ thb,
                                                float* __restrict__ outp){
    __shared__ float smem[16384];   // 64KB: S[32][512]f32 -> P_hi/P_lo bf16 -> ax_hi/lo bf16
    char* sb = (char*)smem;
    // XCD-aware remap (bijective: 3712 = 8 XCDs * 464)
    int i    = blockIdx.x;
    int k_   = i >> 3;
    int bw   = (i & 7) * 29 + (k_ >> 4);
    int tile = k_ & 15;
    int bs   = bw / NWW;
    int w    = bw - bs*NWW;
    int g0   = bs*4096 + w*128;     // window slab base row
    int g032 = bs*128 + w*4;        // g0/32 (m-tile base)
    int tid = threadIdx.x, lane = tid & 63, wid = tid >> 6;
    int lr = lane & 15, g = lane >> 4;

    // ---- Phase 1: S = Q K^T via MFMA; B double-buffered, A single (L1-shared by 8 waves)
    f32x4 acc[2][4];
    #pragma unroll
    for (int qt = 0; qt < 2; ++qt)
        #pragma unroll
        for (int j = 0; j < 4; ++j) acc[qt][j] = (f32x4){0.f,0.f,0.f,0.f};

    int qrow = g0 + tile*32 + lr;
    int brow = g0 + wid*64 + lr;
    {
        bf16x8 A0h, A0l, A1h, A1l;
        bf16x8 cB0h,cB0l,cB1h,cB1l,cB2h,cB2l,cB3h,cB3l;
        bf16x8 nB0h,nB0l,nB1h,nB1l,nB2h,nB2l,nB3h,nB3l;

#define LDA1(KS) { size_t ta=(size_t)(KS)*HT_FT + g*8 + (size_t)qrow*32; \
        A0h=*(const bf16x8*)(Hh+ta);        A0l=*(const bf16x8*)(Hl+ta); \
        A1h=*(const bf16x8*)(Hh+ta+512);    A1l=*(const bf16x8*)(Hl+ta+512); }
#define LDB1(P, KS) { size_t tb=(size_t)(KS)*HT_FT + g*8 + (size_t)brow*32; \
        P##B0h=*(const bf16x8*)(Hh+tb);       P##B0l=*(const bf16x8*)(Hl+tb); \
        P##B1h=*(const bf16x8*)(Hh+tb+512);   P##B1l=*(const bf16x8*)(Hl+tb+512); \
        P##B2h=*(const bf16x8*)(Hh+tb+1024);  P##B2l=*(const bf16x8*)(Hl+tb+1024); \
        P##B3h=*(const bf16x8*)(Hh+tb+1536);  P##B3l=*(const bf16x8*)(Hl+tb+1536); }
#define MM1(P) { \
        acc[0][0]=MFMA16(A0h,P##B0h,acc[0][0]); acc[0][0]=MFMA16(A0h,P##B0l,acc[0][0]); acc[0][0]=MFMA16(A0l,P##B0h,acc[0][0]); \
        acc[1][0]=MFMA16(A1h,P##B0h,acc[1][0]); acc[1][0]=MFMA16(A1h,P##B0l,acc[1][0]); acc[1][0]=MFMA16(A1l,P##B0h,acc[1][0]); \
        acc[0][1]=MFMA16(A0h,P##B1h,acc[0][1]); acc[0][1]=MFMA16(A0h,P##B1l,acc[0][1]); acc[0][1]=MFMA16(A0l,P##B1h,acc[0][1]); \
        acc[1][1]=MFMA16(A1h,P##B1h,acc[1][1]); acc[1][1]=MFMA16(A1h,P##B1l,acc[1][1]); acc[1][1]=MFMA16(A1l,P##B1h,acc[1][1]); \
        acc[0][2]=MFMA16(A0h,P##B2h,acc[0][2]); acc[0][2]=MFMA16(A0h,P##B2l,acc[0][2]); acc[0][2]=MFMA16(A0l,P##B2h,acc[0][2]); \
        acc[1][2]=MFMA16(A1h,P##B2h,acc[1][2]); acc[1][2]=MFMA16(A1h,P##B2l,acc[1][2]); acc[1][2]=MFMA16(A1l,P##B2h,acc[1][2]); \
        acc[0][3]=MFMA16(A0h,P##B3h,acc[0][3]); acc[0][3]=MFMA16(A0h,P##B3l,acc[0][3]); acc[0][3]=MFMA16(A0l,P##B3h,acc[0][3]); \
        acc[1][3]=MFMA16(A1h,P##B3h,acc[1][3]); acc[1][3]=MFMA16(A1h,P##B3l,acc[1][3]); acc[1][3]=MFMA16(A1l,P##B3h,acc[1][3]); }

        LDA1(0); LDB1(c,0);
        #pragma unroll
        for (int ks = 0; ks < 8; ks += 2){
            LDB1(n, ks+1);                 // prefetch next-ks B
            SBAR();                        // pin: n-loads issued before c-MFMAs
            MM1(c);
            LDA1(ks+1);                    // A for n-block (WAR after c-MFMAs)
            if (ks < 6) LDB1(c, ks+2);     // prefetch ks+2
            SBAR();                        // pin before n-MFMAs
            MM1(n);
            if (ks < 6) LDA1(ks+2);
        }
#undef LDA1
#undef LDB1
#undef MM1
    }
    // store S[32][512] f32, byte = (q*2048 + m*4) ^ ((q&7)<<4)
    #pragma unroll
    for (int qt = 0; qt < 2; ++qt)
        #pragma unroll
        for (int j = 0; j < 4; ++j){
            int m = (wid*4 + j)*16 + lr;
            #pragma unroll
            for (int r = 0; r < 4; ++r){
                int q = qt*16 + g*4 + r;
                *(float*)(sb + (((q<<11) + (m<<2)) ^ ((q&7)<<4))) = acc[qt][j][r];
            }
        }
    __syncthreads();

    // ---- Phase 2: softmax * decay (+eye), rows wid*4..+3, lane holds m = 4*lane+jj, 256+4*lane+jj
    float sacc[4][8];
    int mlo = lane << 2;
    int lbase = tile*32 + wid*4;
    int twl   = lbase >> 6;
    const float LOG2D = -0.5145731728297583f;    // log2(0.7)
    float dm0 = exp2f(LOG2D * fabsf((float)(twl - (lane >> 4))));
    float dm1 = exp2f(LOG2D * fabsf((float)(twl - 4 - (lane >> 4))));
    #pragma unroll
    for (int li = 0; li < 4; ++li){
        int q  = wid*4 + li;
        int lg = tile*32 + q;
        int b0 = ((q<<11) + (mlo<<2)) ^ ((q&7)<<4);
        int b1 = ((q<<11) + 1024 + (mlo<<2)) ^ ((q&7)<<4);
        f32x4 s0 = *(const f32x4*)(sb + b0);
        f32x4 s1 = *(const f32x4*)(sb + b1);
        sacc[li][0]=s0[0]; sacc[li][1]=s0[1]; sacc[li][2]=s0[2]; sacc[li][3]=s0[3];
        sacc[li][4]=s1[0]; sacc[li][5]=s1[1]; sacc[li][6]=s1[2]; sacc[li][7]=s1[3];
        #pragma unroll
        for (int jj = 0; jj < 8; ++jj){
            float v = sacc[li][jj];
            int m = ((jj >> 2) << 8) + mlo + (jj & 3);
            if (m == lg) v -= 1e8f;
            v = (v > 0.f) ? v : 0.01f*v;
            sacc[li][jj] = v;
        }
        float mx = sacc[li][0];
        #pragma unroll
        for (int jj = 1; jj < 8; ++jj) mx = fmaxf(mx, sacc[li][jj]);
        #pragma unroll
        for (int off = 32; off >= 1; off >>= 1) mx = fmaxf(mx, __shfl_xor(mx, off, 64));
        float sum = 0.f;
        #pragma unroll
        for (int jj = 0; jj < 8; ++jj){ float e = __expf(sacc[li][jj] - mx); sacc[li][jj] = e; sum += e; }
        #pragma unroll
        for (int off = 32; off >= 1; off >>= 1) sum += __shfl_xor(sum, off, 64);
        float inv = 1.f / sum;
        float f0m = inv * dm0, f1m = inv * dm1;
        sacc[li][0]*=f0m; sacc[li][1]*=f0m; sacc[li][2]*=f0m; sacc[li][3]*=f0m;
        sacc[li][4]*=f1m; sacc[li][5]*=f1m; sacc[li][6]*=f1m; sacc[li][7]*=f1m;
        #pragma unroll
        for (int jj = 0; jj < 8; ++jj){   // + eye (mask diag == 1); softmax diag is exactly 0
            int m = ((jj >> 2) << 8) + mlo + (jj & 3);
            if (m == lg) sacc[li][jj] += 1.0f;
        }
    }
    __syncthreads();   // all waves done reading S

    // write P_hi[32][512]bf16 @0, P_lo @+32KB; byte = (q*1024 + m*2) ^ ((q&7)<<4)
    #pragma unroll
    for (int li = 0; li < 4; ++li){
        int q = wid*4 + li;
        int swz = (q&7) << 4;
        int bA = ((q<<10) + (lane<<3)) ^ swz;
        int bB = ((q<<10) + 512 + (lane<<3)) ^ swz;
        u16 h[8], l[8];
        #pragma unroll
        for (int jj = 0; jj < 8; ++jj){
            float v = sacc[li][jj];
            h[jj] = f2bf(v);
            l[jj] = f2bf(v - bf2f(h[jj]));
        }
        uint2 vh0; vh0.x=(unsigned)h[0]|((unsigned)h[1]<<16); vh0.y=(unsigned)h[2]|((unsigned)h[3]<<16);
        uint2 vh1; vh1.x=(unsigned)h[4]|((unsigned)h[5]<<16); vh1.y=(unsigned)h[6]|((unsigned)h[7]<<16);
        uint2 vl0; vl0.x=(unsigned)l[0]|((unsigned)l[1]<<16); vl0.y=(unsigned)l[2]|((unsigned)l[3]<<16);
        uint2 vl1; vl1.x=(unsigned)l[4]|((unsigned)l[5]<<16); vl1.y=(unsigned)l[6]|((unsigned)l[7]<<16);
        *(uint2*)(sb + bA)         = vh0;
        *(uint2*)(sb + bB)         = vh1;
        *(uint2*)(sb + 32768 + bA) = vl0;
        *(uint2*)(sb + 32768 + bB) = vl1;
    }
    __syncthreads();   // P ready

    // ---- Phase 3: ax = P @ XN via MFMA; P(LDS) and V(XTt) both double-buffered
    f32x4 acc2[2][2];
    #pragma unroll
    for (int qt = 0; qt < 2; ++qt){ acc2[qt][0]=(f32x4){0.f,0.f,0.f,0.f}; acc2[qt][1]=(f32x4){0.f,0.f,0.f,0.f}; }
    int frow = wid*32 + lr;
    {
        bf16x8 cp0h,cp0l,cp1h,cp1l, cv0h,cv0l,cv1h,cv1l;
        bf16x8 np0h,np0l,np1h,np1l, nv0h,nv0l,nv1h,nv1l;

#define LDP3(P, KS) { \
        int pb = (((lr<<10) + (KS)*64 + (g<<4))) ^ ((lr&7)<<4); \
        P##p0h=*(const bf16x8*)(sb + pb);          P##p0l=*(const bf16x8*)(sb + 32768 + pb); \
        P##p1h=*(const bf16x8*)(sb + 16384 + pb);  P##p1l=*(const bf16x8*)(sb + 49152 + pb); \
        size_t vb = (size_t)(g032 + (KS))*XT_MT + g*8 + (size_t)frow*32; \
        P##v0h=*(const bf16x8*)(XTh + vb);         P##v0l=*(const bf16x8*)(XTl + vb); \
        P##v1h=*(const bf16x8*)(XTh + vb + 512);   P##v1l=*(const bf16x8*)(XTl + vb + 512); }
#define MM3(P) { \
        acc2[0][0]=MFMA16(P##p0h,P##v0h,acc2[0][0]); acc2[0][0]=MFMA16(P##p0h,P##v0l,acc2[0][0]); acc2[0][0]=MFMA16(P##p0l,P##v0h,acc2[0][0]); \
        acc2[1][0]=MFMA16(P##p1h,P##v0h,acc2[1][0]); acc2[1][0]=MFMA16(P##p1h,P##v0l,acc2[1][0]); acc2[1][0]=MFMA16(P##p1l,P##v0h,acc2[1][0]); \
        acc2[0][1]=MFMA16(P##p0h,P##v1h,acc2[0][1]); acc2[0][1]=MFMA16(P##p0h,P##v1l,acc2[0][1]); acc2[0][1]=MFMA16(P##p0l,P##v1h,acc2[0][1]); \
        acc2[1][1]=MFMA16(P##p1h,P##v1h,acc2[1][1]); acc2[1][1]=MFMA16(P##p1h,P##v1l,acc2[1][1]); acc2[1][1]=MFMA16(P##p1l,P##v1h,acc2[1][1]); }

        LDP3(c,0);
        #pragma unroll
        for (int ks = 0; ks < 16; ks += 2){
            LDP3(n, ks+1);
            SBAR();
            MM3(c);
            if (ks < 14) LDP3(c, ks+2);
            SBAR();
            MM3(n);
        }
#undef LDP3
#undef MM3
    }
    __syncthreads();   // done reading P

    // write ax_hi[32][256]bf16 @0, ax_lo @+16KB; byte = (q*512 + f*2) ^ ((q&7)<<4)
    #pragma unroll
    for (int qt = 0; qt < 2; ++qt)
        #pragma unroll
        for (int jn = 0; jn < 2; ++jn){
            int f = (wid*2 + jn)*16 + lr;
            #pragma unroll
            for (int r = 0; r < 4; ++r){
                int q = qt*16 + g*4 + r;
                float v = acc2[qt][jn][r];
                u16 h = f2bf(v);
                int byte = ((q<<9) + (f<<1)) ^ ((q&7)<<4);
                *(u16*)(sb + byte)         = h;
                *(u16*)(sb + 16384 + byte) = f2bf(v - bf2f(h));
            }
        }
    __syncthreads();   // ax ready

    // ---- Phase 4: out_pre = ax @ theta + thb via MFMA; double-buffered
    f32x4 acc3[2];
    acc3[0] = (f32x4){0.f,0.f,0.f,0.f};
    acc3[1] = (f32x4){0.f,0.f,0.f,0.f};
    int orow = wid*16 + lr;
    {
        bf16x8 ca0h,ca0l,ca1h,ca1l, cbh,cbl;
        bf16x8 na0h,na0l,na1h,na1l, nbh,nbl;

#define LDP4(P, KS) { \
        int ab = (((lr<<9) + (KS)*64 + (g<<4))) ^ ((lr&7)<<4); \
        P##a0h=*(const bf16x8*)(sb + ab);         P##a0l=*(const bf16x8*)(sb + 16384 + ab); \
        P##a1h=*(const bf16x8*)(sb + 8192 + ab);  P##a1l=*(const bf16x8*)(sb + 24576 + ab); \
        size_t tb = (size_t)(KS)*TH_FT + (size_t)orow*32 + g*8; \
        P##bh=*(const bf16x8*)(THh + tb);         P##bl=*(const bf16x8*)(THl + tb); }
#define MM4(P) { \
        acc3[0]=MFMA16(P##a0h,P##bh,acc3[0]); acc3[0]=MFMA16(P##a0h,P##bl,acc3[0]); acc3[0]=MFMA16(P##a0l,P##bh,acc3[0]); \
        acc3[1]=MFMA16(P##a1h,P##bh,acc3[1]); acc3[1]=MFMA16(P##a1h,P##bl,acc3[1]); acc3[1]=MFMA16(P##a1l,P##bh,acc3[1]); }

        LDP4(c,0);
        #pragma unroll
        for (int ks = 0; ks < 8; ks += 2){
            LDP4(n, ks+1);
            SBAR();
            MM4(c);
            if (ks < 6) LDP4(c, ks+2);
            SBAR();
            MM4(n);
        }
#undef LDP4
#undef MM4
    }
    float tb2 = thb[orow];
    #pragma unroll
    for (int qt = 0; qt < 2; ++qt)
        #pragma unroll
        for (int r = 0; r < 4; ++r){
            int q = qt*16 + g*4 + r;
            size_t R = (size_t)bw*512 + tile*32 + q;
            outp[R*128 + orow] = acc3[qt][r] + tb2;
        }
}

// ---------------- BN1 stats over out_pre (deterministic two-stage)
__global__ __launch_bounds__(256) void k_stats1(const float* __restrict__ outp, float* __restrict__ part1){
    __shared__ float rs[256], rs2[256];
    int tid = threadIdx.x;
    int ch = tid & 127, rh = tid >> 7;
    size_t base = (size_t)blockIdx.x * 116;
    float s = 0.f, s2 = 0.f;
    for (int i = 0; i < 58; ++i){
        float v = outp[(base + rh + 2*i)*128 + ch];
        s += v; s2 += v*v;
    }
    rs[tid] = s; rs2[tid] = s2;
    __syncthreads();
    if (tid < 128){
        part1[blockIdx.x*256 + tid]       = rs[tid] + rs[tid+128];
        part1[blockIdx.x*256 + 128 + tid] = rs2[tid] + rs2[tid+128];
    }
}

__global__ __launch_bounds__(128) void k_fin1(const float* __restrict__ part1,
                                              const float* __restrict__ g1, const float* __restrict__ b1,
                                              float* __restrict__ sc1, float* __restrict__ sh1){
    int ch = threadIdx.x;
    float S = 0.f, S2 = 0.f;
    for (int b = 0; b < 1024; ++b){ S += part1[b*256 + ch]; S2 += part1[b*256 + 128 + ch]; }
    float mean = S / CNTF;
    float var  = S2 / CNTF - mean*mean;
    float sc = g1[ch] * rsqrtf(var + 1e-5f);
    sc1[ch] = sc;
    sh1[ch] = b1[ch] - mean*sc;
}

// ---------------- BN1 apply + leaky + mean-pool over tw
__global__ __launch_bounds__(256) void k_epi(const float* __restrict__ outp,
                                             const float* __restrict__ sc1, const float* __restrict__ sh1,
                                             float* __restrict__ out){
    int idx = blockIdx.x*256 + threadIdx.x;   // < 1900544
    int o = idx & 127;
    int rest = idx >> 7;
    int n = rest & 63;
    int bwq = rest >> 6;
    float sc = sc1[o], sh = sh1[o];
    size_t rowb = ((size_t)bwq*512 + n)*128 + o;
    float acc = 0.f;
    #pragma unroll
    for (int tw = 0; tw < 8; ++tw){
        float v = outp[rowb + (size_t)tw*64*128];
        v = v*sc + sh;
        v = (v > 0.f) ? v : 0.01f*v;
        acc += v;
    }
    out[idx] = acc * 0.125f;
}

extern "C" void kernel_launch(void* const* d_in, const int* in_sizes, int n_in,
                              void* d_out, int out_size, void* d_ws, size_t ws_size,
                              hipStream_t stream) {
    const float* x   = (const float*)d_in[0];
    const float* Wm  = (const float*)d_in[1];
    const float* bm  = (const float*)d_in[2];
    const float* g0  = (const float*)d_in[3];
    const float* b0  = (const float*)d_in[4];
    const float* th  = (const float*)d_in[5];
    const float* thb = (const float*)d_in[6];
    const float* g1  = (const float*)d_in[7];
    const float* b1  = (const float*)d_in[8];
    char* wsb  = (char*)d_ws;
    float* out = (float*)d_out;

    float* part = (float*)(wsb + B_PART);
    float* sc0  = (float*)(wsb + B_SC0);
    float* sh0  = (float*)(wsb + B_SH0);
    float* sc1  = (float*)(wsb + B_SC1);
    float* sh1  = (float*)(wsb + B_SH1);
    u16* Hh  = (u16*)(wsb + B_HH);
    u16* Hl  = (u16*)(wsb + B_HL);
    u16* XTh = (u16*)(wsb + B_XTH);
    u16* XTl = (u16*)(wsb + B_XTL);
    u16* THh = (u16*)(wsb + B_THH);
    u16* THl = (u16*)(wsb + B_THL);
    float* outp = (float*)(wsb + B_OUTP);

    hipLaunchKernelGGL(k_stats0, dim3(512),  dim3(256), 0, stream, x, part);
    hipLaunchKernelGGL(k_fin0,   dim3(1),    dim3(256), 0, stream, part, g0, b0, sc0, sh0);
    hipLaunchKernelGGL(k_prep,   dim3(128),  dim3(256), 0, stream, th, THh, THl);
    hipLaunchKernelGGL(k_map,    dim3(512),  dim3(256), 0, stream, x, Wm, bm, sc0, sh0, Hh, Hl, XTh, XTl);
    hipLaunchKernelGGL(k_attn,   dim3(3712), dim3(512), 0, stream, Hh, Hl, XTh, XTl, THh, THl, thb, outp);
    hipLaunchKernelGGL(k_stats1, dim3(1024), dim3(256), 0, stream, outp, part);
    hipLaunchKernelGGL(k_fin1,   dim3(1),    dim3(128), 0, stream, part, g1, b1, sc1, sh1);
    hipLaunchKernelGGL(k_epi,    dim3(7424), dim3(256), 0, stream, outp, sc1, sh1, out);
}